// Round 1
// baseline (64.334 us; speedup 1.0000x reference)
//
#include <hip/hip_runtime.h>

// reference: out[b,s,:] = emb_weight[ clamp(lookup_table[input_ids[b,s]], 0, 31999) ]
// shapes: input_ids [16,4096] i32, lookup_table [128000] i32, emb_weight [32000,768] f32
// out [16,4096,768] f32

constexpr int EMB_DIM   = 768;            // floats per row
constexpr int ROW_F4    = EMB_DIM / 4;    // 192 float4 per row
constexpr int VOCAB     = 32000;

__global__ __launch_bounds__(256) void token_emb_gather(
    const int*    __restrict__ input_ids,
    const int*    __restrict__ lookup,
    const float4* __restrict__ emb,   // [VOCAB][192]
    float4*       __restrict__ out,   // [ntok][192]
    int ntok)
{
    // blockDim = (64, 4): one wave per token, 4 tokens per block
    int token = blockIdx.x * 4 + threadIdx.y;
    if (token >= ntok) return;

    int id = lookup[input_ids[token]];          // same address across the wave -> broadcast
    id = min(max(id, 0), VOCAB - 1);            // clamp as in reference

    const float4* __restrict__ src = emb + (size_t)id    * ROW_F4;
    float4*       __restrict__ dst = out + (size_t)token * ROW_F4;

    int lane = threadIdx.x;                     // 0..63
#pragma unroll
    for (int k = 0; k < 3; ++k) {               // 192 = 64 lanes * 3
        dst[lane + 64 * k] = src[lane + 64 * k];
    }
}

extern "C" void kernel_launch(void* const* d_in, const int* in_sizes, int n_in,
                              void* d_out, int out_size, void* d_ws, size_t ws_size,
                              hipStream_t stream)
{
    const int*    input_ids = (const int*)d_in[0];
    const int*    lookup    = (const int*)d_in[1];
    const float4* emb       = (const float4*)d_in[2];
    float4*       out       = (float4*)d_out;

    int ntok = in_sizes[0];                     // 16*4096 = 65536

    dim3 block(64, 4);
    dim3 grid((ntok + 3) / 4);
    token_emb_gather<<<grid, block, 0, stream>>>(input_ids, lookup, emb, out, ntok);
}

// Round 3
// 63.971 us; speedup vs baseline: 1.0057x; 1.0057x over previous
//
#include <hip/hip_runtime.h>

// reference: out[b,s,:] = emb_weight[ clamp(lookup_table[input_ids[b,s]], 0, 31999) ]
// shapes: input_ids [16,4096] i32, lookup_table [128000] i32, emb_weight [32000,768] f32
// out [16,4096,768] f32

constexpr int EMB_DIM   = 768;            // floats per row
constexpr int ROW_F4    = EMB_DIM / 4;    // 192 float4 per row
constexpr int VOCAB     = 32000;

typedef float vfloat4 __attribute__((ext_vector_type(4)));  // native vector for nontemporal builtin

__global__ __launch_bounds__(256) void token_emb_gather(
    const int*     __restrict__ input_ids,
    const int*     __restrict__ lookup,
    const vfloat4* __restrict__ emb,   // [VOCAB][192]
    vfloat4*       __restrict__ out,   // [ntok][192]
    int ntok)
{
    // blockDim = (64, 4): one wave per token, 4 tokens per block
    int token = blockIdx.x * 4 + threadIdx.y;
    if (token >= ntok) return;

    // Dependent index chain: same address across the wave -> broadcast loads.
    int id = lookup[input_ids[token]];
    id = min(max(id, 0), VOCAB - 1);            // clamp as in reference

    const vfloat4* __restrict__ src = emb + (size_t)id    * ROW_F4;
    vfloat4*       __restrict__ dst = out + (size_t)token * ROW_F4;

    int lane = threadIdx.x;                     // 0..63

    // Read row through the cache hierarchy (emb table is hot in L3);
    // write output non-temporally so the 201 MB stream doesn't evict it.
    vfloat4 v0 = src[lane];
    vfloat4 v1 = src[lane + 64];
    vfloat4 v2 = src[lane + 128];
    __builtin_nontemporal_store(v0, &dst[lane]);
    __builtin_nontemporal_store(v1, &dst[lane + 64]);
    __builtin_nontemporal_store(v2, &dst[lane + 128]);
}

extern "C" void kernel_launch(void* const* d_in, const int* in_sizes, int n_in,
                              void* d_out, int out_size, void* d_ws, size_t ws_size,
                              hipStream_t stream)
{
    const int*     input_ids = (const int*)d_in[0];
    const int*     lookup    = (const int*)d_in[1];
    const vfloat4* emb       = (const vfloat4*)d_in[2];
    vfloat4*       out       = (vfloat4*)d_out;

    int ntok = in_sizes[0];                     // 16*4096 = 65536

    dim3 block(64, 4);
    dim3 grid((ntok + 3) / 4);
    token_emb_gather<<<grid, block, 0, stream>>>(input_ids, lookup, emb, out, ntok);
}

// Round 4
// 63.072 us; speedup vs baseline: 1.0200x; 1.0143x over previous
//
#include <hip/hip_runtime.h>

// reference: out[b,s,:] = emb_weight[ clamp(lookup_table[input_ids[b,s]], 0, 31999) ]
// shapes: input_ids [16,4096] i32, lookup_table [128000] i32, emb_weight [32000,768] f32
// out [16,4096,768] f32
//
// R3 finding: plain + __builtin_nontemporal_store both land at 64 us =
// (write 201MB + read ~201MB)/6.3 TB/s -> no L3 read-reuse captured; the
// write stream thrashes the MALL. This round: maximally write-around stores
// (global_store_dwordx4 ... sc0 sc1 nt) so the 98MB emb table stays MALL-
// resident across graph replays.

constexpr int EMB_DIM   = 768;            // floats per row
constexpr int ROW_F4    = EMB_DIM / 4;    // 192 float4 per row
constexpr int VOCAB     = 32000;

typedef float vfloat4 __attribute__((ext_vector_type(4)));

__device__ __forceinline__ void store_nt_wa(vfloat4* p, vfloat4 v) {
    // write-around at every cache level: sc0 sc1 (system scope) + nt
    asm volatile("global_store_dwordx4 %0, %1, off sc0 sc1 nt"
                 :: "v"(p), "v"(v) : "memory");
}

__global__ __launch_bounds__(256) void token_emb_gather(
    const int*     __restrict__ input_ids,
    const int*     __restrict__ lookup,
    const vfloat4* __restrict__ emb,   // [VOCAB][192]
    vfloat4*       __restrict__ out,   // [ntok][192]
    int ntok)
{
    // blockDim = (64, 4): one wave per token, 4 tokens per block
    int token = blockIdx.x * 4 + threadIdx.y;
    if (token >= ntok) return;

    int id = lookup[input_ids[token]];          // wave-uniform -> broadcast
    id = min(max(id, 0), VOCAB - 1);            // clamp as in reference

    const vfloat4* __restrict__ src = emb + (size_t)id    * ROW_F4;
    vfloat4*       __restrict__ dst = out + (size_t)token * ROW_F4;

    int lane = threadIdx.x;                     // 0..63

    vfloat4 v0 = src[lane];
    vfloat4 v1 = src[lane + 64];
    vfloat4 v2 = src[lane + 128];
    store_nt_wa(dst + lane,       v0);
    store_nt_wa(dst + lane + 64,  v1);
    store_nt_wa(dst + lane + 128, v2);
}

extern "C" void kernel_launch(void* const* d_in, const int* in_sizes, int n_in,
                              void* d_out, int out_size, void* d_ws, size_t ws_size,
                              hipStream_t stream)
{
    const int*     input_ids = (const int*)d_in[0];
    const int*     lookup    = (const int*)d_in[1];
    const vfloat4* emb       = (const vfloat4*)d_in[2];
    vfloat4*       out       = (vfloat4*)d_out;

    int ntok = in_sizes[0];                     // 16*4096 = 65536

    dim3 block(64, 4);
    dim3 grid((ntok + 3) / 4);
    token_emb_gather<<<grid, block, 0, stream>>>(input_ids, lookup, emb, out, ntok);
}